// Round 9
// baseline (4920.703 us; speedup 1.0000x reference)
//
#include <hip/hip_runtime.h>
#include <hip/hip_fp16.h>

typedef _Float16 half8 __attribute__((ext_vector_type(8)));
typedef float floatx4 __attribute__((ext_vector_type(4)));

#define DEV static __device__ __forceinline__

DEV float sigmoidf_(float x) { return 1.f / (1.f + __expf(-x)); }
DEV float tanh_fast(float x) {
    x = fminf(fmaxf(x, -15.f), 15.f);
    float e2 = __expf(2.f * x);
    return (e2 - 1.f) / (e2 + 1.f);
}
DEV unsigned short f2h_(float f) {
    __half h = __float2half_rn(f);
    return *reinterpret_cast<unsigned short*>(&h);
}
DEV float h2f_(unsigned short u) {
    __half h = *reinterpret_cast<__half*>(&u);
    return __half2float(h);
}
DEV float loadElem(const float* p) { return *p; }
DEV float loadElem(const unsigned short* p) { return h2f_(*p); }
DEV void storeMsg(float* p, float v) { *p = v; }
DEV void storeMsg(unsigned short* p, float v) { *p = f2h_(v); }

// ---- A-fragment loaders: 8 contiguous elements, as half8 ------------------
DEV half8 afrag(const float* __restrict__ p, unsigned off) {
    float4 a = *reinterpret_cast<const float4*>(p + off);
    float4 b = *reinterpret_cast<const float4*>(p + off + 4);
    half8 h;
    h[0] = (_Float16)a.x; h[1] = (_Float16)a.y; h[2] = (_Float16)a.z; h[3] = (_Float16)a.w;
    h[4] = (_Float16)b.x; h[5] = (_Float16)b.y; h[6] = (_Float16)b.z; h[7] = (_Float16)b.w;
    return h;
}
DEV half8 afrag(const unsigned short* __restrict__ p, unsigned off) {
    uint4 v = *reinterpret_cast<const uint4*>(p + off);
    return __builtin_bit_cast(half8, v);
}
DEV half8 h8load(const _Float16* __restrict__ p) {
    return *reinterpret_cast<const half8*>(p);
}
// ef[k] = relu(er*We[k]+be[k]) for k = k0..k0+7, as half8
DEV half8 effrag(float er, const float* __restrict__ We,
                 const float* __restrict__ be, int k0) {
    float4 w0 = *reinterpret_cast<const float4*>(We + k0);
    float4 w1 = *reinterpret_cast<const float4*>(We + k0 + 4);
    float4 b0 = *reinterpret_cast<const float4*>(be + k0);
    float4 b1 = *reinterpret_cast<const float4*>(be + k0 + 4);
    half8 h;
    h[0] = (_Float16)fmaxf(fmaf(er, w0.x, b0.x), 0.f);
    h[1] = (_Float16)fmaxf(fmaf(er, w0.y, b0.y), 0.f);
    h[2] = (_Float16)fmaxf(fmaf(er, w0.z, b0.z), 0.f);
    h[3] = (_Float16)fmaxf(fmaf(er, w0.w, b0.w), 0.f);
    h[4] = (_Float16)fmaxf(fmaf(er, w1.x, b1.x), 0.f);
    h[5] = (_Float16)fmaxf(fmaf(er, w1.y, b1.y), 0.f);
    h[6] = (_Float16)fmaxf(fmaf(er, w1.z, b1.z), 0.f);
    h[7] = (_Float16)fmaxf(fmaf(er, w1.w, b1.w), 0.f);
    return h;
}
DEV void load8(const float* __restrict__ p, float x[8]) {
    const float4* q = reinterpret_cast<const float4*>(p);
    float4 a = q[0], b = q[1];
    x[0] = a.x; x[1] = a.y; x[2] = a.z; x[3] = a.w;
    x[4] = b.x; x[5] = b.y; x[6] = b.z; x[7] = b.w;
}

// ---------------------------------------------------------------------------
// CSR build over tgt (int atomics only)
// ---------------------------------------------------------------------------
__global__ void k_deg(const int* __restrict__ tgt, int* __restrict__ deg, int E) {
    int e = blockIdx.x * blockDim.x + threadIdx.x;
    if (e < E) atomicAdd(&deg[tgt[e]], 1);
}

__global__ __launch_bounds__(1024)
void k_scan(const int* __restrict__ deg, int* __restrict__ row_ptr,
            int* __restrict__ cursor, int N) {
    __shared__ int part[1024];
    int tid = threadIdx.x;
    int chunk = (N + 1023) / 1024;
    int lo = tid * chunk, hi = min(lo + chunk, N);
    int s = 0;
    for (int i = lo; i < hi; i++) s += deg[i];
    part[tid] = s;
    __syncthreads();
    for (int off = 1; off < 1024; off <<= 1) {
        int v = (tid >= off) ? part[tid - off] : 0;
        __syncthreads();
        part[tid] += v;
        __syncthreads();
    }
    int base = (tid == 0) ? 0 : part[tid - 1];
    for (int i = lo; i < hi; i++) {
        row_ptr[i] = base;
        cursor[i] = base;
        base += deg[i];
    }
    if (tid == 1023) row_ptr[N] = part[1023];
}

__global__ void k_fill(const int* __restrict__ tgt, int* __restrict__ cursor,
                       int* __restrict__ col_idx, int E) {
    int e = blockIdx.x * blockDim.x + threadIdx.x;
    if (e < E) {
        int pos = atomicAdd(&cursor[tgt[e]], 1);
        col_idx[pos] = e;
    }
}

// ---------------------------------------------------------------------------
// Weight prep: fp16 repack. WmeT[64][128], WmpT[64][64], WibT[64][64],
// WihP[192][64], WhhP[192][64].
// ---------------------------------------------------------------------------
__global__ void k_prep(const float* __restrict__ Wme, const float* __restrict__ Wmp,
                       const float* __restrict__ Wi, const float* __restrict__ Wih,
                       const float* __restrict__ Whh, _Float16* __restrict__ wp) {
    int t = blockIdx.x * blockDim.x + threadIdx.x;
    if (t < 8192) { int n = t >> 7, k = t & 127; wp[t] = (_Float16)Wme[k * 64 + n]; return; }
    int u = t - 8192;
    if (u < 4096) { int n = u >> 6, k = u & 63; wp[8192 + u] = (_Float16)Wmp[k * 64 + n]; return; }
    u -= 4096;
    if (u < 4096) { int n = u >> 6, k = u & 63; wp[12288 + u] = (_Float16)Wi[(64 + k) * 64 + n]; return; }
    u -= 4096;
    if (u < 12288) { wp[16384 + u] = (_Float16)Wih[u]; return; }
    u -= 12288;
    if (u < 12288) { wp[28672 + u] = (_Float16)Whh[u]; return; }
}

// ---------------------------------------------------------------------------
// k_zn: per node, zn = nf @ Wi_top + b_init
// ---------------------------------------------------------------------------
__global__ __launch_bounds__(256)
void k_zn(const float* __restrict__ prob, const float* __restrict__ seedp,
          const float* __restrict__ Wn, const float* __restrict__ bn,
          const float* __restrict__ Wi, const float* __restrict__ bi,
          float* __restrict__ zn, int N) {
    int n = blockIdx.x * blockDim.x + threadIdx.x;
    if (n >= N) return;
    float p = prob[n], sd = seedp[n];
    float acc[64];
#pragma unroll
    for (int j = 0; j < 64; j++) acc[j] = bi[j];
#pragma unroll 1
    for (int k = 0; k < 64; k++) {
        float nf = fmaxf(fmaf(p, Wn[k], fmaf(sd, Wn[64 + k], bn[k])), 0.f);
        const float* w = Wi + k * 64;
#pragma unroll
        for (int j = 0; j < 64; j++) acc[j] = fmaf(nf, w[j], acc[j]);
    }
    float4* q = reinterpret_cast<float4*>(zn + (size_t)n * 64);
#pragma unroll
    for (int c = 0; c < 16; c++)
        q[c] = make_float4(acc[4 * c], acc[4 * c + 1], acc[4 * c + 2], acc[4 * c + 3]);
}

// ---------------------------------------------------------------------------
// k_init_mfma: message = relu(zn[src] + ef@WibT)
// ---------------------------------------------------------------------------
template <typename MsgT, bool FULL>
__global__ __launch_bounds__(256)
void k_init_mfma(const int* __restrict__ src, const float* __restrict__ eraw,
                 const float* __restrict__ We, const float* __restrict__ be,
                 const _Float16* __restrict__ WibT, const float* __restrict__ zn,
                 MsgT* __restrict__ message, int row_off, int E) {
    int wid = (blockIdx.x * blockDim.x + threadIdx.x) >> 6;
    int rowbase = row_off + wid * 64;
    if (rowbase >= E) return;
    int lane = threadIdx.x & 63, q = lane >> 4, m16 = lane & 15, kq8 = q * 8;
    floatx4 zero4 = {0.f, 0.f, 0.f, 0.f};
    floatx4 acc[4][4];
#pragma unroll
    for (int a = 0; a < 4; a++)
#pragma unroll
        for (int b = 0; b < 4; b++) acc[a][b] = zero4;
#pragma unroll
    for (int ks = 0; ks < 2; ks++) {
        int k0 = ks * 32 + kq8;
        half8 B[4];
#pragma unroll
        for (int nt = 0; nt < 4; nt++) B[nt] = h8load(WibT + (nt * 16 + m16) * 64 + k0);
#pragma unroll
        for (int rt = 0; rt < 4; rt++) {
            int row = rowbase + rt * 16 + m16;
            if (!FULL) row = min(row, E - 1);
            half8 A = effrag(eraw[row], We, be, k0);
#pragma unroll
            for (int nt = 0; nt < 4; nt++)
                acc[rt][nt] = __builtin_amdgcn_mfma_f32_16x16x32_f16(A, B[nt], acc[rt][nt], 0, 0, 0);
        }
    }
#pragma unroll
    for (int nt = 0; nt < 4; nt++) {
        int col = nt * 16 + m16;
#pragma unroll
        for (int rt = 0; rt < 4; rt++)
#pragma unroll
            for (int r = 0; r < 4; r++) {
                int row = rowbase + rt * 16 + q * 4 + r;
                if (FULL || row < E) {
                    int s = src[row];
                    float v = acc[rt][nt][r] + zn[(unsigned)s * 64u + col];
                    storeMsg(message + (unsigned)row * 64u + col, fmaxf(v, 0.f));
                }
            }
    }
}

// ---------------------------------------------------------------------------
// k_edge_m_mfma: m = relu([message, ef] @ WmeT^T + bme) -> m_buf (fp16)
// ---------------------------------------------------------------------------
template <typename MsgT, bool FULL>
__global__ __launch_bounds__(256)
void k_edge_m_mfma(const float* __restrict__ eraw, const float* __restrict__ We,
                   const float* __restrict__ be, const _Float16* __restrict__ WmeT,
                   const float* __restrict__ bme, const MsgT* __restrict__ message,
                   unsigned short* __restrict__ m_buf, int row_off, int E) {
    int wid = (blockIdx.x * blockDim.x + threadIdx.x) >> 6;
    int rowbase = row_off + wid * 64;
    if (rowbase >= E) return;
    int lane = threadIdx.x & 63, q = lane >> 4, m16 = lane & 15, kq8 = q * 8;
    floatx4 zero4 = {0.f, 0.f, 0.f, 0.f};
    floatx4 acc[4][4];
#pragma unroll
    for (int a = 0; a < 4; a++)
#pragma unroll
        for (int b = 0; b < 4; b++) acc[a][b] = zero4;
#pragma unroll
    for (int ks = 0; ks < 4; ks++) {
        int k0 = ks * 32 + kq8;
        half8 B[4];
#pragma unroll
        for (int nt = 0; nt < 4; nt++) B[nt] = h8load(WmeT + (nt * 16 + m16) * 128 + k0);
#pragma unroll
        for (int rt = 0; rt < 4; rt++) {
            int row = rowbase + rt * 16 + m16;
            if (!FULL) row = min(row, E - 1);
            half8 A = (ks < 2) ? afrag(message + (unsigned)row * 64u, k0)
                               : effrag(eraw[row], We, be, k0 - 64);
#pragma unroll
            for (int nt = 0; nt < 4; nt++)
                acc[rt][nt] = __builtin_amdgcn_mfma_f32_16x16x32_f16(A, B[nt], acc[rt][nt], 0, 0, 0);
        }
    }
#pragma unroll
    for (int nt = 0; nt < 4; nt++) {
        int col = nt * 16 + m16;
        float bb = bme[col];
#pragma unroll
        for (int rt = 0; rt < 4; rt++)
#pragma unroll
            for (int r = 0; r < 4; r++) {
                int row = rowbase + rt * 16 + q * 4 + r;
                if (FULL || row < E)
                    m_buf[(unsigned)row * 64u + col] = f2h_(fmaxf(acc[rt][nt][r] + bb, 0.f));
            }
    }
}

// ---------------------------------------------------------------------------
// k_gru_mfma: u GEMM -> LDS transform -> 6 gate GEMMs -> gate math ->
//   in-place message update. h re-materialized in C-layout via identity-MFMA
//   (Dh = ah · I), replacing 64 scalar 2B reloads per lane.
// ---------------------------------------------------------------------------
template <typename MsgT, bool FULL>
__global__ __launch_bounds__(256)
void k_gru_mfma(const int* __restrict__ src, const int* __restrict__ rev,
                const float* __restrict__ node_agg,
                const unsigned short* __restrict__ m_buf,
                const _Float16* __restrict__ WmpT, const float* __restrict__ bmp,
                const _Float16* __restrict__ WihP, const _Float16* __restrict__ WhhP,
                const float* __restrict__ bih, const float* __restrict__ bhh,
                MsgT* __restrict__ message, int row_off, int E) {
    __shared__ _Float16 uT[4][64 * 72];
    int wid = (blockIdx.x * blockDim.x + threadIdx.x) >> 6;
    int rowbase = row_off + wid * 64;
    if (rowbase >= E) return;
    int w = threadIdx.x >> 6;
    int lane = threadIdx.x & 63, q = lane >> 4, m16 = lane & 15, kq8 = q * 8;
    floatx4 zero4 = {0.f, 0.f, 0.f, 0.f};

    // phase 1: u = relu((node_agg[src] - m_buf[rev]) @ WmpT^T + bmp)
    floatx4 accU[4][4];
#pragma unroll
    for (int a = 0; a < 4; a++)
#pragma unroll
        for (int b = 0; b < 4; b++) accU[a][b] = zero4;
#pragma unroll
    for (int ks = 0; ks < 2; ks++) {
        int k0 = ks * 32 + kq8;
        half8 B[4];
#pragma unroll
        for (int nt = 0; nt < 4; nt++) B[nt] = h8load(WmpT + (nt * 16 + m16) * 64 + k0);
#pragma unroll
        for (int rt = 0; rt < 4; rt++) {
            int row = rowbase + rt * 16 + m16;
            if (!FULL) row = min(row, E - 1);
            int s = src[row], rv = rev[row];
            const float* na = node_agg + (unsigned)s * 64u + k0;
            float4 a0 = *reinterpret_cast<const float4*>(na);
            float4 a1 = *reinterpret_cast<const float4*>(na + 4);
            uint4 mv = *reinterpret_cast<const uint4*>(m_buf + (unsigned)rv * 64u + k0);
            half8 mh = __builtin_bit_cast(half8, mv);
            half8 A;
            A[0] = (_Float16)(a0.x - (float)mh[0]); A[1] = (_Float16)(a0.y - (float)mh[1]);
            A[2] = (_Float16)(a0.z - (float)mh[2]); A[3] = (_Float16)(a0.w - (float)mh[3]);
            A[4] = (_Float16)(a1.x - (float)mh[4]); A[5] = (_Float16)(a1.y - (float)mh[5]);
            A[6] = (_Float16)(a1.z - (float)mh[6]); A[7] = (_Float16)(a1.w - (float)mh[7]);
#pragma unroll
            for (int nt = 0; nt < 4; nt++)
                accU[rt][nt] = __builtin_amdgcn_mfma_f32_16x16x32_f16(A, B[nt], accU[rt][nt], 0, 0, 0);
        }
    }
    // u epilogue -> LDS (D-layout to row-major fp16)
#pragma unroll
    for (int nt = 0; nt < 4; nt++) {
        int col = nt * 16 + m16;
        float bb = bmp[col];
#pragma unroll
        for (int rt = 0; rt < 4; rt++)
#pragma unroll
            for (int r = 0; r < 4; r++) {
                int rl = rt * 16 + q * 4 + r;
                uT[w][rl * 72 + col] = (_Float16)fmaxf(accU[rt][nt][r] + bb, 0.f);
            }
    }
    // phase 2: A-fragments of u (LDS) and h (global message)
    half8 au[4][2], ah[4][2];
#pragma unroll
    for (int rt = 0; rt < 4; rt++)
#pragma unroll
        for (int ks = 0; ks < 2; ks++) {
            au[rt][ks] = *reinterpret_cast<const half8*>(
                &uT[w][(rt * 16 + m16) * 72 + ks * 32 + kq8]);
            int row = rowbase + rt * 16 + m16;
            if (!FULL) row = min(row, E - 1);
            ah[rt][ks] = afrag(message + (unsigned)row * 64u, ks * 32 + kq8);
        }
    // phase 3: per 16-col group: 6 gate GEMMs + identity-MFMA h + gate math
#pragma unroll 1
    for (int nt = 0; nt < 4; nt++) {
        int col = nt * 16 + m16;
        half8 Bir[2], Biz[2], Bin[2], Bhr[2], Bhz[2], Bhn[2];
#pragma unroll
        for (int ks = 0; ks < 2; ks++) {
            int k0 = ks * 32 + kq8;
            Bir[ks] = h8load(WihP + (unsigned)(0 + col) * 64u + k0);
            Biz[ks] = h8load(WihP + (unsigned)(64 + col) * 64u + k0);
            Bin[ks] = h8load(WihP + (unsigned)(128 + col) * 64u + k0);
            Bhr[ks] = h8load(WhhP + (unsigned)(0 + col) * 64u + k0);
            Bhz[ks] = h8load(WhhP + (unsigned)(64 + col) * 64u + k0);
            Bhn[ks] = h8load(WhhP + (unsigned)(128 + col) * 64u + k0);
        }
        // identity B-fragment: I[k][n]=1 iff k==nt*16+n; only ks=nt>>1 matters
        int tgtk = (nt & 1) * 16 + m16;
        half8 If;
#pragma unroll
        for (int j = 0; j < 8; j++) If[j] = (_Float16)((kq8 + j == tgtk) ? 1.f : 0.f);
        int ksI = nt >> 1;
        floatx4 ar[4], az[4], ain[4], ahn[4], Dh[4];
#pragma unroll
        for (int rt = 0; rt < 4; rt++) {
            ar[rt] = zero4; az[rt] = zero4; ain[rt] = zero4; ahn[rt] = zero4;
            Dh[rt] = __builtin_amdgcn_mfma_f32_16x16x32_f16(ah[rt][ksI], If, zero4, 0, 0, 0);
        }
#pragma unroll
        for (int ks = 0; ks < 2; ks++)
#pragma unroll
            for (int rt = 0; rt < 4; rt++) {
                ar[rt] = __builtin_amdgcn_mfma_f32_16x16x32_f16(au[rt][ks], Bir[ks], ar[rt], 0, 0, 0);
                ar[rt] = __builtin_amdgcn_mfma_f32_16x16x32_f16(ah[rt][ks], Bhr[ks], ar[rt], 0, 0, 0);
                az[rt] = __builtin_amdgcn_mfma_f32_16x16x32_f16(au[rt][ks], Biz[ks], az[rt], 0, 0, 0);
                az[rt] = __builtin_amdgcn_mfma_f32_16x16x32_f16(ah[rt][ks], Bhz[ks], az[rt], 0, 0, 0);
                ain[rt] = __builtin_amdgcn_mfma_f32_16x16x32_f16(au[rt][ks], Bin[ks], ain[rt], 0, 0, 0);
                ahn[rt] = __builtin_amdgcn_mfma_f32_16x16x32_f16(ah[rt][ks], Bhn[ks], ahn[rt], 0, 0, 0);
            }
        float br_ = bih[col] + bhh[col];
        float bz_ = bih[64 + col] + bhh[64 + col];
        float bin_ = bih[128 + col];
        float bhn_ = bhh[128 + col];
#pragma unroll
        for (int rt = 0; rt < 4; rt++)
#pragma unroll
            for (int r = 0; r < 4; r++) {
                int row = rowbase + rt * 16 + q * 4 + r;
                if (FULL || row < E) {
                    float rr = sigmoidf_(ar[rt][r] + br_);
                    float zz = sigmoidf_(az[rt][r] + bz_);
                    float nn = tanh_fast(ain[rt][r] + bin_ + rr * (ahn[rt][r] + bhn_));
                    float hv = Dh[rt][r];
                    storeMsg(message + (unsigned)row * 64u + col, fmaf(zz, hv - nn, nn));
                }
            }
    }
}

// ---------------------------------------------------------------------------
// k_agg: wave-per-node coalesced gather-sum (lane j = feature j)
// ---------------------------------------------------------------------------
template <typename T>
__global__ __launch_bounds__(256)
void k_agg(const int* __restrict__ row_ptr, const int* __restrict__ col_idx,
           const T* __restrict__ rows, float* __restrict__ out, int N) {
    int wid = (blockIdx.x * blockDim.x + threadIdx.x) >> 6;
    int lane = threadIdx.x & 63;
    if (wid >= N) return;
    int beg = row_ptr[wid], end = row_ptr[wid + 1];
    float acc = 0.f;
    int i = beg;
    for (; i + 3 < end; i += 4) {
        int e0 = __builtin_amdgcn_readfirstlane(col_idx[i]);
        int e1 = __builtin_amdgcn_readfirstlane(col_idx[i + 1]);
        int e2 = __builtin_amdgcn_readfirstlane(col_idx[i + 2]);
        int e3 = __builtin_amdgcn_readfirstlane(col_idx[i + 3]);
        acc += loadElem(rows + (unsigned)e0 * 64u + lane);
        acc += loadElem(rows + (unsigned)e1 * 64u + lane);
        acc += loadElem(rows + (unsigned)e2 * 64u + lane);
        acc += loadElem(rows + (unsigned)e3 * 64u + lane);
    }
    for (; i < end; i++) {
        int e0 = __builtin_amdgcn_readfirstlane(col_idx[i]);
        acc += loadElem(rows + (unsigned)e0 * 64u + lane);
    }
    out[(unsigned)wid * 64u + lane] = acc;
}

// ---------------------------------------------------------------------------
// k_nodes: agg MLP + out MLP + log_softmax + delta(atomicMax on fp32 bits)
// ---------------------------------------------------------------------------
__global__ __launch_bounds__(256, 2)
void k_nodes(const float* __restrict__ node_agg, const float* __restrict__ prob,
             const float* __restrict__ seedp,
             const float* __restrict__ Wn, const float* __restrict__ bn,
             const float* __restrict__ Wa, const float* __restrict__ ba,
             const float* __restrict__ Wo, const float* __restrict__ bo,
             float* __restrict__ marg, float* __restrict__ prev_p2,
             float* __restrict__ deltas_f, int layer, int N) {
    int n = blockIdx.x * blockDim.x + threadIdx.x;
    if (n >= N) return;
    float a[64];
#pragma unroll
    for (int j = 0; j < 64; j++) a[j] = ba[j];
    const float* ag = node_agg + (size_t)n * 64;
#pragma unroll 1
    for (int c = 0; c < 8; c++) {
        float v[8];
        load8(ag + 8 * c, v);
#pragma unroll
        for (int i = 0; i < 8; i++) {
            const float* w = Wa + (8 * c + i) * 64;
#pragma unroll
            for (int j = 0; j < 64; j++) a[j] = fmaf(v[i], w[j], a[j]);
        }
    }
    float l0 = bo[0], l1 = bo[1], l2 = bo[2];
#pragma unroll
    for (int k = 0; k < 64; k++) {
        float ak = fmaxf(a[k], 0.f);
        l0 = fmaf(ak, Wo[k * 3 + 0], l0);
        l1 = fmaf(ak, Wo[k * 3 + 1], l1);
        l2 = fmaf(ak, Wo[k * 3 + 2], l2);
    }
    float p = prob[n], sd = seedp[n];
#pragma unroll 1
    for (int k = 0; k < 64; k++) {
        float nf = fmaxf(fmaf(p, Wn[k], fmaf(sd, Wn[64 + k], bn[k])), 0.f);
        l0 = fmaf(nf, Wo[(64 + k) * 3 + 0], l0);
        l1 = fmaf(nf, Wo[(64 + k) * 3 + 1], l1);
        l2 = fmaf(nf, Wo[(64 + k) * 3 + 2], l2);
    }
    l0 = fmaxf(l0, 0.f); l1 = fmaxf(l1, 0.f); l2 = fmaxf(l2, 0.f);
    float mx = fmaxf(l0, fmaxf(l1, l2));
    float ssum = __expf(l0 - mx) + __expf(l1 - mx) + __expf(l2 - mx);
    float lse = mx + logf(ssum);
    float o0 = l0 - lse, o1 = l1 - lse, o2 = l2 - lse;
    float* out = marg + ((size_t)layer * N + n) * 3;
    out[0] = o0; out[1] = o1; out[2] = o2;
    float p2 = __expf(o2);
    if (layer > 0) {
        float d = fabsf(p2 - prev_p2[n]);
        atomicMax(reinterpret_cast<unsigned int*>(deltas_f + (layer - 1)),
                  __float_as_uint(d));
    }
    prev_p2[n] = p2;
}

__global__ void k_deltas_out(const float* __restrict__ deltas_f,
                             float* __restrict__ out, int L) {
    int i = threadIdx.x;
    if (i < L) out[i] = deltas_f[i];
}

// ---------------------------------------------------------------------------
template <typename MsgT>
static void run_pipeline(void* const* d_in, int E, int N, MsgT* message,
                         unsigned short* m_buf, float* node_agg, _Float16* wp,
                         int* deg, int* row_ptr, int* cursor, int* col_idx,
                         float* prev_p2, float* deltas_f, float* marg,
                         float* deltas_out, hipStream_t stream) {
    const int* src = (const int*)d_in[0];
    const int* tgt = (const int*)d_in[1];
    const int* rev = (const int*)d_in[2];
    const float* eraw = (const float*)d_in[3];
    const float* prob = (const float*)d_in[4];
    const float* seedp = (const float*)d_in[5];
    const float* Wn = (const float*)d_in[6];  const float* bn = (const float*)d_in[7];
    const float* We = (const float*)d_in[8];  const float* be = (const float*)d_in[9];
    const float* Wi = (const float*)d_in[10]; const float* bi = (const float*)d_in[11];
    const float* Wa = (const float*)d_in[12]; const float* ba = (const float*)d_in[13];
    const float* Wo = (const float*)d_in[14]; const float* bo = (const float*)d_in[15];
    const float* Wme = (const float*)d_in[16]; const float* bme = (const float*)d_in[17];
    const float* Wmp = (const float*)d_in[18]; const float* bmp = (const float*)d_in[19];
    const float* Wih = (const float*)d_in[20]; const float* Whh = (const float*)d_in[21];
    const float* bih = (const float*)d_in[22]; const float* bhh = (const float*)d_in[23];

    const _Float16* WmeT = wp;
    const _Float16* WmpT = wp + 8192;
    const _Float16* WibT = wp + 12288;
    const _Float16* WihP = wp + 16384;
    const _Float16* WhhP = wp + 28672;

    const int L = 4;
    dim3 blk(256);
    dim3 eg((E + 255) / 256), ng((N + 255) / 256);
    dim3 ag((N + 3) / 4);
    // full-tile blocks (256 rows each) + optional 1-block clamped tail
    int fullb = E / 256;
    int tail_off = fullb * 256;
    bool tail = (tail_off < E);

    hipMemsetAsync(deg, 0, (size_t)N * 4, stream);
    hipMemsetAsync(deltas_f, 0, L * sizeof(float), stream);
    k_deg<<<eg, blk, 0, stream>>>(tgt, deg, E);
    k_scan<<<1, 1024, 0, stream>>>(deg, row_ptr, cursor, N);
    k_fill<<<eg, blk, 0, stream>>>(tgt, cursor, col_idx, E);
    k_prep<<<160, 256, 0, stream>>>(Wme, Wmp, Wi, Wih, Whh, wp);
    k_zn<<<ng, blk, 0, stream>>>(prob, seedp, Wn, bn, Wi, bi, node_agg, N);

    if (fullb)
        k_init_mfma<MsgT, true><<<fullb, blk, 0, stream>>>(src, eraw, We, be, WibT,
                                                           node_agg, message, 0, E);
    if (tail)
        k_init_mfma<MsgT, false><<<1, blk, 0, stream>>>(src, eraw, We, be, WibT,
                                                        node_agg, message, tail_off, E);
    k_agg<MsgT><<<ag, blk, 0, stream>>>(row_ptr, col_idx, message, node_agg, N);
    k_nodes<<<ng, blk, 0, stream>>>(node_agg, prob, seedp, Wn, bn, Wa, ba, Wo, bo,
                                    marg, prev_p2, deltas_f, 0, N);
    for (int l = 0; l < L; l++) {
        if (fullb)
            k_edge_m_mfma<MsgT, true><<<fullb, blk, 0, stream>>>(eraw, We, be, WmeT, bme,
                                                                 message, m_buf, 0, E);
        if (tail)
            k_edge_m_mfma<MsgT, false><<<1, blk, 0, stream>>>(eraw, We, be, WmeT, bme,
                                                              message, m_buf, tail_off, E);
        k_agg<unsigned short><<<ag, blk, 0, stream>>>(row_ptr, col_idx, m_buf,
                                                      node_agg, N);
        if (fullb)
            k_gru_mfma<MsgT, true><<<fullb, blk, 0, stream>>>(src, rev, node_agg, m_buf,
                                                              WmpT, bmp, WihP, WhhP,
                                                              bih, bhh, message, 0, E);
        if (tail)
            k_gru_mfma<MsgT, false><<<1, blk, 0, stream>>>(src, rev, node_agg, m_buf,
                                                           WmpT, bmp, WihP, WhhP,
                                                           bih, bhh, message, tail_off, E);
        k_agg<MsgT><<<ag, blk, 0, stream>>>(row_ptr, col_idx, message, node_agg, N);
        k_nodes<<<ng, blk, 0, stream>>>(node_agg, prob, seedp, Wn, bn, Wa, ba,
                                        Wo, bo, marg, prev_p2, deltas_f, l + 1, N);
    }
    k_deltas_out<<<1, 64, 0, stream>>>(deltas_f, deltas_out, L);
}

extern "C" void kernel_launch(void* const* d_in, const int* in_sizes, int n_in,
                              void* d_out, int out_size, void* d_ws, size_t ws_size,
                              hipStream_t stream) {
    const int E = in_sizes[0];
    const int N = in_sizes[4];
    const int L = 4, S = 3;

    float* marg = (float*)d_out;                         // [(L+1),N,S] fp32
    float* deltas_out = marg + (size_t)(L + 1) * N * S;  // [L] fp32

    char* ws = (char*)d_ws;
    float* deltas_f = (float*)ws;                        // 4 (16B slot)
    float* prev_p2 = (float*)(ws + 16);                  // N
    int* deg = (int*)(prev_p2 + N);                      // N
    int* row_ptr = deg + N;                              // N+1
    int* cursor = row_ptr + N + 1;                       // N
    int* col_idx = cursor + N;                           // E
    char* p = (char*)(col_idx + E);
    p = (char*)(((uintptr_t)p + 255) & ~(uintptr_t)255);
    _Float16* wp = (_Float16*)p;                         // 40960 halves
    p += 40960 * 2;
    p = (char*)(((uintptr_t)p + 255) & ~(uintptr_t)255);
    float* node_agg = (float*)p;                         // N*64 (also zn)
    p += (size_t)N * 64 * 4;
    p = (char*)(((uintptr_t)p + 255) & ~(uintptr_t)255);
    size_t head = (size_t)(p - ws);
    size_t msg_f32 = (size_t)E * 64 * 4;
    size_t msg_f16 = (size_t)E * 64 * 2;
    size_t m_f16 = (size_t)E * 64 * 2;

    if (ws_size >= head + msg_f32 + m_f16) {
        // Tier A: fp32 message + fp16 m_buf
        float* message = (float*)p;
        unsigned short* m_buf = (unsigned short*)(p + msg_f32);
        run_pipeline<float>(d_in, E, N, message, m_buf, node_agg, wp,
                            deg, row_ptr, cursor, col_idx,
                            prev_p2, deltas_f, marg, deltas_out, stream);
    } else {
        // Tier B: fp16 message + fp16 m_buf
        unsigned short* message = (unsigned short*)p;
        unsigned short* m_buf = (unsigned short*)(p + msg_f16);
        run_pipeline<unsigned short>(d_in, E, N, message, m_buf, node_agg, wp,
                                     deg, row_ptr, cursor, col_idx,
                                     prev_p2, deltas_f, marg, deltas_out, stream);
    }
}

// Round 10
// 1997.884 us; speedup vs baseline: 2.4630x; 2.4630x over previous
//
#include <hip/hip_runtime.h>
#include <hip/hip_fp16.h>

typedef _Float16 half8 __attribute__((ext_vector_type(8)));
typedef float floatx4 __attribute__((ext_vector_type(4)));

#define DEV static __device__ __forceinline__

DEV float sigmoidf_(float x) { return 1.f / (1.f + __expf(-x)); }
DEV float tanh_fast(float x) {
    x = fminf(fmaxf(x, -15.f), 15.f);
    float e2 = __expf(2.f * x);
    return (e2 - 1.f) / (e2 + 1.f);
}
DEV unsigned short f2h_(float f) {
    __half h = __float2half_rn(f);
    return *reinterpret_cast<unsigned short*>(&h);
}
DEV float h2f_(unsigned short u) {
    __half h = *reinterpret_cast<__half*>(&u);
    return __half2float(h);
}
DEV float loadElem(const float* p) { return *p; }
DEV float loadElem(const unsigned short* p) { return h2f_(*p); }
DEV void storeMsg(float* p, float v) { *p = v; }
DEV void storeMsg(unsigned short* p, float v) { *p = f2h_(v); }

// ---- A-fragment loaders: 8 contiguous elements, as half8 ------------------
DEV half8 afrag(const float* __restrict__ p, unsigned off) {
    float4 a = *reinterpret_cast<const float4*>(p + off);
    float4 b = *reinterpret_cast<const float4*>(p + off + 4);
    half8 h;
    h[0] = (_Float16)a.x; h[1] = (_Float16)a.y; h[2] = (_Float16)a.z; h[3] = (_Float16)a.w;
    h[4] = (_Float16)b.x; h[5] = (_Float16)b.y; h[6] = (_Float16)b.z; h[7] = (_Float16)b.w;
    return h;
}
DEV half8 afrag(const unsigned short* __restrict__ p, unsigned off) {
    uint4 v = *reinterpret_cast<const uint4*>(p + off);
    return __builtin_bit_cast(half8, v);
}
DEV half8 h8load(const _Float16* __restrict__ p) {
    return *reinterpret_cast<const half8*>(p);
}
// ef[k] = relu(er*We[k]+be[k]) for k = k0..k0+7, as half8
DEV half8 effrag(float er, const float* __restrict__ We,
                 const float* __restrict__ be, int k0) {
    float4 w0 = *reinterpret_cast<const float4*>(We + k0);
    float4 w1 = *reinterpret_cast<const float4*>(We + k0 + 4);
    float4 b0 = *reinterpret_cast<const float4*>(be + k0);
    float4 b1 = *reinterpret_cast<const float4*>(be + k0 + 4);
    half8 h;
    h[0] = (_Float16)fmaxf(fmaf(er, w0.x, b0.x), 0.f);
    h[1] = (_Float16)fmaxf(fmaf(er, w0.y, b0.y), 0.f);
    h[2] = (_Float16)fmaxf(fmaf(er, w0.z, b0.z), 0.f);
    h[3] = (_Float16)fmaxf(fmaf(er, w0.w, b0.w), 0.f);
    h[4] = (_Float16)fmaxf(fmaf(er, w1.x, b1.x), 0.f);
    h[5] = (_Float16)fmaxf(fmaf(er, w1.y, b1.y), 0.f);
    h[6] = (_Float16)fmaxf(fmaf(er, w1.z, b1.z), 0.f);
    h[7] = (_Float16)fmaxf(fmaf(er, w1.w, b1.w), 0.f);
    return h;
}
DEV void load8(const float* __restrict__ p, float x[8]) {
    const float4* q = reinterpret_cast<const float4*>(p);
    float4 a = q[0], b = q[1];
    x[0] = a.x; x[1] = a.y; x[2] = a.z; x[3] = a.w;
    x[4] = b.x; x[5] = b.y; x[6] = b.z; x[7] = b.w;
}

// ---------------------------------------------------------------------------
// CSR build over tgt (int atomics only)
// ---------------------------------------------------------------------------
__global__ void k_deg(const int* __restrict__ tgt, int* __restrict__ deg, int E) {
    int e = blockIdx.x * blockDim.x + threadIdx.x;
    if (e < E) atomicAdd(&deg[tgt[e]], 1);
}

__global__ __launch_bounds__(1024)
void k_scan(const int* __restrict__ deg, int* __restrict__ row_ptr,
            int* __restrict__ cursor, int N) {
    __shared__ int part[1024];
    int tid = threadIdx.x;
    int chunk = (N + 1023) / 1024;
    int lo = tid * chunk, hi = min(lo + chunk, N);
    int s = 0;
    for (int i = lo; i < hi; i++) s += deg[i];
    part[tid] = s;
    __syncthreads();
    for (int off = 1; off < 1024; off <<= 1) {
        int v = (tid >= off) ? part[tid - off] : 0;
        __syncthreads();
        part[tid] += v;
        __syncthreads();
    }
    int base = (tid == 0) ? 0 : part[tid - 1];
    for (int i = lo; i < hi; i++) {
        row_ptr[i] = base;
        cursor[i] = base;
        base += deg[i];
    }
    if (tid == 1023) row_ptr[N] = part[1023];
}

__global__ void k_fill(const int* __restrict__ tgt, int* __restrict__ cursor,
                       int* __restrict__ col_idx, int E) {
    int e = blockIdx.x * blockDim.x + threadIdx.x;
    if (e < E) {
        int pos = atomicAdd(&cursor[tgt[e]], 1);
        col_idx[pos] = e;
    }
}

// ---------------------------------------------------------------------------
// Weight prep: fp16 repack. WmeT[64][128], WmpT[64][64], WibT[64][64],
// WihP[192][64], WhhP[192][64].
// ---------------------------------------------------------------------------
__global__ void k_prep(const float* __restrict__ Wme, const float* __restrict__ Wmp,
                       const float* __restrict__ Wi, const float* __restrict__ Wih,
                       const float* __restrict__ Whh, _Float16* __restrict__ wp) {
    int t = blockIdx.x * blockDim.x + threadIdx.x;
    if (t < 8192) { int n = t >> 7, k = t & 127; wp[t] = (_Float16)Wme[k * 64 + n]; return; }
    int u = t - 8192;
    if (u < 4096) { int n = u >> 6, k = u & 63; wp[8192 + u] = (_Float16)Wmp[k * 64 + n]; return; }
    u -= 4096;
    if (u < 4096) { int n = u >> 6, k = u & 63; wp[12288 + u] = (_Float16)Wi[(64 + k) * 64 + n]; return; }
    u -= 4096;
    if (u < 12288) { wp[16384 + u] = (_Float16)Wih[u]; return; }
    u -= 12288;
    if (u < 12288) { wp[28672 + u] = (_Float16)Whh[u]; return; }
}

// ---------------------------------------------------------------------------
// k_zn: per node, zn = nf @ Wi_top + b_init
// ---------------------------------------------------------------------------
__global__ __launch_bounds__(256)
void k_zn(const float* __restrict__ prob, const float* __restrict__ seedp,
          const float* __restrict__ Wn, const float* __restrict__ bn,
          const float* __restrict__ Wi, const float* __restrict__ bi,
          float* __restrict__ zn, int N) {
    int n = blockIdx.x * blockDim.x + threadIdx.x;
    if (n >= N) return;
    float p = prob[n], sd = seedp[n];
    float acc[64];
#pragma unroll
    for (int j = 0; j < 64; j++) acc[j] = bi[j];
#pragma unroll 1
    for (int k = 0; k < 64; k++) {
        float nf = fmaxf(fmaf(p, Wn[k], fmaf(sd, Wn[64 + k], bn[k])), 0.f);
        const float* w = Wi + k * 64;
#pragma unroll
        for (int j = 0; j < 64; j++) acc[j] = fmaf(nf, w[j], acc[j]);
    }
    float4* q = reinterpret_cast<float4*>(zn + (size_t)n * 64);
#pragma unroll
    for (int c = 0; c < 16; c++)
        q[c] = make_float4(acc[4 * c], acc[4 * c + 1], acc[4 * c + 2], acc[4 * c + 3]);
}

// ---------------------------------------------------------------------------
// k_init_mfma: message = relu(zn[src] + ef@WibT)
// ---------------------------------------------------------------------------
template <typename MsgT, bool FULL>
__global__ __launch_bounds__(256)
void k_init_mfma(const int* __restrict__ src, const float* __restrict__ eraw,
                 const float* __restrict__ We, const float* __restrict__ be,
                 const _Float16* __restrict__ WibT, const float* __restrict__ zn,
                 MsgT* __restrict__ message, int row_off, int E) {
    int wid = (blockIdx.x * blockDim.x + threadIdx.x) >> 6;
    int rowbase = row_off + wid * 64;
    if (rowbase >= E) return;
    int lane = threadIdx.x & 63, q = lane >> 4, m16 = lane & 15, kq8 = q * 8;
    floatx4 zero4 = {0.f, 0.f, 0.f, 0.f};
    floatx4 acc[4][4];
#pragma unroll
    for (int a = 0; a < 4; a++)
#pragma unroll
        for (int b = 0; b < 4; b++) acc[a][b] = zero4;
#pragma unroll
    for (int ks = 0; ks < 2; ks++) {
        int k0 = ks * 32 + kq8;
        half8 B[4];
#pragma unroll
        for (int nt = 0; nt < 4; nt++) B[nt] = h8load(WibT + (nt * 16 + m16) * 64 + k0);
#pragma unroll
        for (int rt = 0; rt < 4; rt++) {
            int row = rowbase + rt * 16 + m16;
            if (!FULL) row = min(row, E - 1);
            half8 A = effrag(eraw[row], We, be, k0);
#pragma unroll
            for (int nt = 0; nt < 4; nt++)
                acc[rt][nt] = __builtin_amdgcn_mfma_f32_16x16x32_f16(A, B[nt], acc[rt][nt], 0, 0, 0);
        }
    }
#pragma unroll
    for (int nt = 0; nt < 4; nt++) {
        int col = nt * 16 + m16;
#pragma unroll
        for (int rt = 0; rt < 4; rt++)
#pragma unroll
            for (int r = 0; r < 4; r++) {
                int row = rowbase + rt * 16 + q * 4 + r;
                if (FULL || row < E) {
                    int s = src[row];
                    float v = acc[rt][nt][r] + zn[(unsigned)s * 64u + col];
                    storeMsg(message + (unsigned)row * 64u + col, fmaxf(v, 0.f));
                }
            }
    }
}

// ---------------------------------------------------------------------------
// k_edge_m_mfma: m = relu([message, ef] @ WmeT^T + bme) -> m_buf (fp16)
// ---------------------------------------------------------------------------
template <typename MsgT, bool FULL>
__global__ __launch_bounds__(256)
void k_edge_m_mfma(const float* __restrict__ eraw, const float* __restrict__ We,
                   const float* __restrict__ be, const _Float16* __restrict__ WmeT,
                   const float* __restrict__ bme, const MsgT* __restrict__ message,
                   unsigned short* __restrict__ m_buf, int row_off, int E) {
    int wid = (blockIdx.x * blockDim.x + threadIdx.x) >> 6;
    int rowbase = row_off + wid * 64;
    if (rowbase >= E) return;
    int lane = threadIdx.x & 63, q = lane >> 4, m16 = lane & 15, kq8 = q * 8;
    floatx4 zero4 = {0.f, 0.f, 0.f, 0.f};
    floatx4 acc[4][4];
#pragma unroll
    for (int a = 0; a < 4; a++)
#pragma unroll
        for (int b = 0; b < 4; b++) acc[a][b] = zero4;
#pragma unroll
    for (int ks = 0; ks < 4; ks++) {
        int k0 = ks * 32 + kq8;
        half8 B[4];
#pragma unroll
        for (int nt = 0; nt < 4; nt++) B[nt] = h8load(WmeT + (nt * 16 + m16) * 128 + k0);
#pragma unroll
        for (int rt = 0; rt < 4; rt++) {
            int row = rowbase + rt * 16 + m16;
            if (!FULL) row = min(row, E - 1);
            half8 A = (ks < 2) ? afrag(message + (unsigned)row * 64u, k0)
                               : effrag(eraw[row], We, be, k0 - 64);
#pragma unroll
            for (int nt = 0; nt < 4; nt++)
                acc[rt][nt] = __builtin_amdgcn_mfma_f32_16x16x32_f16(A, B[nt], acc[rt][nt], 0, 0, 0);
        }
    }
#pragma unroll
    for (int nt = 0; nt < 4; nt++) {
        int col = nt * 16 + m16;
        float bb = bme[col];
#pragma unroll
        for (int rt = 0; rt < 4; rt++)
#pragma unroll
            for (int r = 0; r < 4; r++) {
                int row = rowbase + rt * 16 + q * 4 + r;
                if (FULL || row < E)
                    m_buf[(unsigned)row * 64u + col] = f2h_(fmaxf(acc[rt][nt][r] + bb, 0.f));
            }
    }
}

// ---------------------------------------------------------------------------
// k_gru_mfma: u GEMM -> LDS transform -> 6 gate GEMMs -> gate math ->
//   in-place message update. h read via scalar L1-hit reloads in the epilogue
//   (R9's identity-MFMA variant raised VGPR 108->180, halved occupancy: reverted).
// ---------------------------------------------------------------------------
template <typename MsgT, bool FULL>
__global__ __launch_bounds__(256)
void k_gru_mfma(const int* __restrict__ src, const int* __restrict__ rev,
                const float* __restrict__ node_agg,
                const unsigned short* __restrict__ m_buf,
                const _Float16* __restrict__ WmpT, const float* __restrict__ bmp,
                const _Float16* __restrict__ WihP, const _Float16* __restrict__ WhhP,
                const float* __restrict__ bih, const float* __restrict__ bhh,
                MsgT* __restrict__ message, int row_off, int E) {
    __shared__ _Float16 uT[4][64 * 72];
    int wid = (blockIdx.x * blockDim.x + threadIdx.x) >> 6;
    int rowbase = row_off + wid * 64;
    if (rowbase >= E) return;
    int w = threadIdx.x >> 6;
    int lane = threadIdx.x & 63, q = lane >> 4, m16 = lane & 15, kq8 = q * 8;
    floatx4 zero4 = {0.f, 0.f, 0.f, 0.f};

    // phase 1: u = relu((node_agg[src] - m_buf[rev]) @ WmpT^T + bmp)
    floatx4 accU[4][4];
#pragma unroll
    for (int a = 0; a < 4; a++)
#pragma unroll
        for (int b = 0; b < 4; b++) accU[a][b] = zero4;
#pragma unroll
    for (int ks = 0; ks < 2; ks++) {
        int k0 = ks * 32 + kq8;
        half8 B[4];
#pragma unroll
        for (int nt = 0; nt < 4; nt++) B[nt] = h8load(WmpT + (nt * 16 + m16) * 64 + k0);
#pragma unroll
        for (int rt = 0; rt < 4; rt++) {
            int row = rowbase + rt * 16 + m16;
            if (!FULL) row = min(row, E - 1);
            int s = src[row], rv = rev[row];
            const float* na = node_agg + (unsigned)s * 64u + k0;
            float4 a0 = *reinterpret_cast<const float4*>(na);
            float4 a1 = *reinterpret_cast<const float4*>(na + 4);
            uint4 mv = *reinterpret_cast<const uint4*>(m_buf + (unsigned)rv * 64u + k0);
            half8 mh = __builtin_bit_cast(half8, mv);
            half8 A;
            A[0] = (_Float16)(a0.x - (float)mh[0]); A[1] = (_Float16)(a0.y - (float)mh[1]);
            A[2] = (_Float16)(a0.z - (float)mh[2]); A[3] = (_Float16)(a0.w - (float)mh[3]);
            A[4] = (_Float16)(a1.x - (float)mh[4]); A[5] = (_Float16)(a1.y - (float)mh[5]);
            A[6] = (_Float16)(a1.z - (float)mh[6]); A[7] = (_Float16)(a1.w - (float)mh[7]);
#pragma unroll
            for (int nt = 0; nt < 4; nt++)
                accU[rt][nt] = __builtin_amdgcn_mfma_f32_16x16x32_f16(A, B[nt], accU[rt][nt], 0, 0, 0);
        }
    }
    // u epilogue -> LDS (D-layout to row-major fp16)
#pragma unroll
    for (int nt = 0; nt < 4; nt++) {
        int col = nt * 16 + m16;
        float bb = bmp[col];
#pragma unroll
        for (int rt = 0; rt < 4; rt++)
#pragma unroll
            for (int r = 0; r < 4; r++) {
                int rl = rt * 16 + q * 4 + r;
                uT[w][rl * 72 + col] = (_Float16)fmaxf(accU[rt][nt][r] + bb, 0.f);
            }
    }
    // phase 2: A-fragments of u (LDS) and h (global message)
    half8 au[4][2], ah[4][2];
#pragma unroll
    for (int rt = 0; rt < 4; rt++)
#pragma unroll
        for (int ks = 0; ks < 2; ks++) {
            au[rt][ks] = *reinterpret_cast<const half8*>(
                &uT[w][(rt * 16 + m16) * 72 + ks * 32 + kq8]);
            int row = rowbase + rt * 16 + m16;
            if (!FULL) row = min(row, E - 1);
            ah[rt][ks] = afrag(message + (unsigned)row * 64u, ks * 32 + kq8);
        }
    // phase 3: per 16-col group: 6 gate GEMMs + gate math + store
#pragma unroll 1
    for (int nt = 0; nt < 4; nt++) {
        int col = nt * 16 + m16;
        half8 Bir[2], Biz[2], Bin[2], Bhr[2], Bhz[2], Bhn[2];
#pragma unroll
        for (int ks = 0; ks < 2; ks++) {
            int k0 = ks * 32 + kq8;
            Bir[ks] = h8load(WihP + (unsigned)(0 + col) * 64u + k0);
            Biz[ks] = h8load(WihP + (unsigned)(64 + col) * 64u + k0);
            Bin[ks] = h8load(WihP + (unsigned)(128 + col) * 64u + k0);
            Bhr[ks] = h8load(WhhP + (unsigned)(0 + col) * 64u + k0);
            Bhz[ks] = h8load(WhhP + (unsigned)(64 + col) * 64u + k0);
            Bhn[ks] = h8load(WhhP + (unsigned)(128 + col) * 64u + k0);
        }
        floatx4 ar[4], az[4], ain[4], ahn[4];
#pragma unroll
        for (int rt = 0; rt < 4; rt++) { ar[rt] = zero4; az[rt] = zero4; ain[rt] = zero4; ahn[rt] = zero4; }
#pragma unroll
        for (int ks = 0; ks < 2; ks++)
#pragma unroll
            for (int rt = 0; rt < 4; rt++) {
                ar[rt] = __builtin_amdgcn_mfma_f32_16x16x32_f16(au[rt][ks], Bir[ks], ar[rt], 0, 0, 0);
                ar[rt] = __builtin_amdgcn_mfma_f32_16x16x32_f16(ah[rt][ks], Bhr[ks], ar[rt], 0, 0, 0);
                az[rt] = __builtin_amdgcn_mfma_f32_16x16x32_f16(au[rt][ks], Biz[ks], az[rt], 0, 0, 0);
                az[rt] = __builtin_amdgcn_mfma_f32_16x16x32_f16(ah[rt][ks], Bhz[ks], az[rt], 0, 0, 0);
                ain[rt] = __builtin_amdgcn_mfma_f32_16x16x32_f16(au[rt][ks], Bin[ks], ain[rt], 0, 0, 0);
                ahn[rt] = __builtin_amdgcn_mfma_f32_16x16x32_f16(ah[rt][ks], Bhn[ks], ahn[rt], 0, 0, 0);
            }
        float br_ = bih[col] + bhh[col];
        float bz_ = bih[64 + col] + bhh[64 + col];
        float bin_ = bih[128 + col];
        float bhn_ = bhh[128 + col];
#pragma unroll
        for (int rt = 0; rt < 4; rt++)
#pragma unroll
            for (int r = 0; r < 4; r++) {
                int row = rowbase + rt * 16 + q * 4 + r;
                if (FULL || row < E) {
                    float rr = sigmoidf_(ar[rt][r] + br_);
                    float zz = sigmoidf_(az[rt][r] + bz_);
                    float nn = tanh_fast(ain[rt][r] + bin_ + rr * (ahn[rt][r] + bhn_));
                    MsgT* mp = message + (unsigned)row * 64u + col;
                    float hv = loadElem(mp);  // L1 hit
                    storeMsg(mp, fmaf(zz, hv - nn, nn));
                }
            }
    }
}

// ---------------------------------------------------------------------------
// k_agg: wave-per-node coalesced gather-sum (lane j = feature j)
// ---------------------------------------------------------------------------
template <typename T>
__global__ __launch_bounds__(256)
void k_agg(const int* __restrict__ row_ptr, const int* __restrict__ col_idx,
           const T* __restrict__ rows, float* __restrict__ out, int N) {
    int wid = (blockIdx.x * blockDim.x + threadIdx.x) >> 6;
    int lane = threadIdx.x & 63;
    if (wid >= N) return;
    int beg = row_ptr[wid], end = row_ptr[wid + 1];
    float acc = 0.f;
    int i = beg;
    for (; i + 3 < end; i += 4) {
        int e0 = __builtin_amdgcn_readfirstlane(col_idx[i]);
        int e1 = __builtin_amdgcn_readfirstlane(col_idx[i + 1]);
        int e2 = __builtin_amdgcn_readfirstlane(col_idx[i + 2]);
        int e3 = __builtin_amdgcn_readfirstlane(col_idx[i + 3]);
        acc += loadElem(rows + (unsigned)e0 * 64u + lane);
        acc += loadElem(rows + (unsigned)e1 * 64u + lane);
        acc += loadElem(rows + (unsigned)e2 * 64u + lane);
        acc += loadElem(rows + (unsigned)e3 * 64u + lane);
    }
    for (; i < end; i++) {
        int e0 = __builtin_amdgcn_readfirstlane(col_idx[i]);
        acc += loadElem(rows + (unsigned)e0 * 64u + lane);
    }
    out[(unsigned)wid * 64u + lane] = acc;
}

// ---------------------------------------------------------------------------
// k_nodes: agg MLP + out MLP + log_softmax + delta(atomicMax on fp32 bits)
// ---------------------------------------------------------------------------
__global__ __launch_bounds__(256, 2)
void k_nodes(const float* __restrict__ node_agg, const float* __restrict__ prob,
             const float* __restrict__ seedp,
             const float* __restrict__ Wn, const float* __restrict__ bn,
             const float* __restrict__ Wa, const float* __restrict__ ba,
             const float* __restrict__ Wo, const float* __restrict__ bo,
             float* __restrict__ marg, float* __restrict__ prev_p2,
             float* __restrict__ deltas_f, int layer, int N) {
    int n = blockIdx.x * blockDim.x + threadIdx.x;
    if (n >= N) return;
    float a[64];
#pragma unroll
    for (int j = 0; j < 64; j++) a[j] = ba[j];
    const float* ag = node_agg + (size_t)n * 64;
#pragma unroll 1
    for (int c = 0; c < 8; c++) {
        float v[8];
        load8(ag + 8 * c, v);
#pragma unroll
        for (int i = 0; i < 8; i++) {
            const float* w = Wa + (8 * c + i) * 64;
#pragma unroll
            for (int j = 0; j < 64; j++) a[j] = fmaf(v[i], w[j], a[j]);
        }
    }
    float l0 = bo[0], l1 = bo[1], l2 = bo[2];
#pragma unroll
    for (int k = 0; k < 64; k++) {
        float ak = fmaxf(a[k], 0.f);
        l0 = fmaf(ak, Wo[k * 3 + 0], l0);
        l1 = fmaf(ak, Wo[k * 3 + 1], l1);
        l2 = fmaf(ak, Wo[k * 3 + 2], l2);
    }
    float p = prob[n], sd = seedp[n];
#pragma unroll 1
    for (int k = 0; k < 64; k++) {
        float nf = fmaxf(fmaf(p, Wn[k], fmaf(sd, Wn[64 + k], bn[k])), 0.f);
        l0 = fmaf(nf, Wo[(64 + k) * 3 + 0], l0);
        l1 = fmaf(nf, Wo[(64 + k) * 3 + 1], l1);
        l2 = fmaf(nf, Wo[(64 + k) * 3 + 2], l2);
    }
    l0 = fmaxf(l0, 0.f); l1 = fmaxf(l1, 0.f); l2 = fmaxf(l2, 0.f);
    float mx = fmaxf(l0, fmaxf(l1, l2));
    float ssum = __expf(l0 - mx) + __expf(l1 - mx) + __expf(l2 - mx);
    float lse = mx + logf(ssum);
    float o0 = l0 - lse, o1 = l1 - lse, o2 = l2 - lse;
    float* out = marg + ((size_t)layer * N + n) * 3;
    out[0] = o0; out[1] = o1; out[2] = o2;
    float p2 = __expf(o2);
    if (layer > 0) {
        float d = fabsf(p2 - prev_p2[n]);
        atomicMax(reinterpret_cast<unsigned int*>(deltas_f + (layer - 1)),
                  __float_as_uint(d));
    }
    prev_p2[n] = p2;
}

__global__ void k_deltas_out(const float* __restrict__ deltas_f,
                             float* __restrict__ out, int L) {
    int i = threadIdx.x;
    if (i < L) out[i] = deltas_f[i];
}

// ---------------------------------------------------------------------------
template <typename MsgT>
static void run_pipeline(void* const* d_in, int E, int N, MsgT* message,
                         unsigned short* m_buf, float* node_agg, _Float16* wp,
                         int* deg, int* row_ptr, int* cursor, int* col_idx,
                         float* prev_p2, float* deltas_f, float* marg,
                         float* deltas_out, hipStream_t stream) {
    const int* src = (const int*)d_in[0];
    const int* tgt = (const int*)d_in[1];
    const int* rev = (const int*)d_in[2];
    const float* eraw = (const float*)d_in[3];
    const float* prob = (const float*)d_in[4];
    const float* seedp = (const float*)d_in[5];
    const float* Wn = (const float*)d_in[6];  const float* bn = (const float*)d_in[7];
    const float* We = (const float*)d_in[8];  const float* be = (const float*)d_in[9];
    const float* Wi = (const float*)d_in[10]; const float* bi = (const float*)d_in[11];
    const float* Wa = (const float*)d_in[12]; const float* ba = (const float*)d_in[13];
    const float* Wo = (const float*)d_in[14]; const float* bo = (const float*)d_in[15];
    const float* Wme = (const float*)d_in[16]; const float* bme = (const float*)d_in[17];
    const float* Wmp = (const float*)d_in[18]; const float* bmp = (const float*)d_in[19];
    const float* Wih = (const float*)d_in[20]; const float* Whh = (const float*)d_in[21];
    const float* bih = (const float*)d_in[22]; const float* bhh = (const float*)d_in[23];

    const _Float16* WmeT = wp;
    const _Float16* WmpT = wp + 8192;
    const _Float16* WibT = wp + 12288;
    const _Float16* WihP = wp + 16384;
    const _Float16* WhhP = wp + 28672;

    const int L = 4;
    dim3 blk(256);
    dim3 eg((E + 255) / 256), ng((N + 255) / 256);
    dim3 ag((N + 3) / 4);
    int fullb = E / 256;
    int tail_off = fullb * 256;
    bool tail = (tail_off < E);

    hipMemsetAsync(deg, 0, (size_t)N * 4, stream);
    hipMemsetAsync(deltas_f, 0, L * sizeof(float), stream);
    k_deg<<<eg, blk, 0, stream>>>(tgt, deg, E);
    k_scan<<<1, 1024, 0, stream>>>(deg, row_ptr, cursor, N);
    k_fill<<<eg, blk, 0, stream>>>(tgt, cursor, col_idx, E);
    k_prep<<<160, 256, 0, stream>>>(Wme, Wmp, Wi, Wih, Whh, wp);
    k_zn<<<ng, blk, 0, stream>>>(prob, seedp, Wn, bn, Wi, bi, node_agg, N);

    if (fullb)
        k_init_mfma<MsgT, true><<<fullb, blk, 0, stream>>>(src, eraw, We, be, WibT,
                                                           node_agg, message, 0, E);
    if (tail)
        k_init_mfma<MsgT, false><<<1, blk, 0, stream>>>(src, eraw, We, be, WibT,
                                                        node_agg, message, tail_off, E);
    k_agg<MsgT><<<ag, blk, 0, stream>>>(row_ptr, col_idx, message, node_agg, N);
    k_nodes<<<ng, blk, 0, stream>>>(node_agg, prob, seedp, Wn, bn, Wa, ba, Wo, bo,
                                    marg, prev_p2, deltas_f, 0, N);
    for (int l = 0; l < L; l++) {
        if (fullb)
            k_edge_m_mfma<MsgT, true><<<fullb, blk, 0, stream>>>(eraw, We, be, WmeT, bme,
                                                                 message, m_buf, 0, E);
        if (tail)
            k_edge_m_mfma<MsgT, false><<<1, blk, 0, stream>>>(eraw, We, be, WmeT, bme,
                                                              message, m_buf, tail_off, E);
        k_agg<unsigned short><<<ag, blk, 0, stream>>>(row_ptr, col_idx, m_buf,
                                                      node_agg, N);
        if (fullb)
            k_gru_mfma<MsgT, true><<<fullb, blk, 0, stream>>>(src, rev, node_agg, m_buf,
                                                              WmpT, bmp, WihP, WhhP,
                                                              bih, bhh, message, 0, E);
        if (tail)
            k_gru_mfma<MsgT, false><<<1, blk, 0, stream>>>(src, rev, node_agg, m_buf,
                                                           WmpT, bmp, WihP, WhhP,
                                                           bih, bhh, message, tail_off, E);
        k_agg<MsgT><<<ag, blk, 0, stream>>>(row_ptr, col_idx, message, node_agg, N);
        k_nodes<<<ng, blk, 0, stream>>>(node_agg, prob, seedp, Wn, bn, Wa, ba,
                                        Wo, bo, marg, prev_p2, deltas_f, l + 1, N);
    }
    k_deltas_out<<<1, 64, 0, stream>>>(deltas_f, deltas_out, L);
}

extern "C" void kernel_launch(void* const* d_in, const int* in_sizes, int n_in,
                              void* d_out, int out_size, void* d_ws, size_t ws_size,
                              hipStream_t stream) {
    const int E = in_sizes[0];
    const int N = in_sizes[4];
    const int L = 4, S = 3;

    float* marg = (float*)d_out;                         // [(L+1),N,S] fp32
    float* deltas_out = marg + (size_t)(L + 1) * N * S;  // [L] fp32

    char* ws = (char*)d_ws;
    float* deltas_f = (float*)ws;                        // 4 (16B slot)
    float* prev_p2 = (float*)(ws + 16);                  // N
    int* deg = (int*)(prev_p2 + N);                      // N
    int* row_ptr = deg + N;                              // N+1
    int* cursor = row_ptr + N + 1;                       // N
    int* col_idx = cursor + N;                           // E
    char* p = (char*)(col_idx + E);
    p = (char*)(((uintptr_t)p + 255) & ~(uintptr_t)255);
    _Float16* wp = (_Float16*)p;                         // 40960 halves
    p += 40960 * 2;
    p = (char*)(((uintptr_t)p + 255) & ~(uintptr_t)255);
    float* node_agg = (float*)p;                         // N*64 (also zn)
    p += (size_t)N * 64 * 4;
    p = (char*)(((uintptr_t)p + 255) & ~(uintptr_t)255);
    size_t head = (size_t)(p - ws);
    size_t msg_f32 = (size_t)E * 64 * 4;
    size_t msg_f16 = (size_t)E * 64 * 2;
    size_t m_f16 = (size_t)E * 64 * 2;

    if (ws_size >= head + msg_f32 + m_f16) {
        // Tier A: fp32 message + fp16 m_buf
        float* message = (float*)p;
        unsigned short* m_buf = (unsigned short*)(p + msg_f32);
        run_pipeline<float>(d_in, E, N, message, m_buf, node_agg, wp,
                            deg, row_ptr, cursor, col_idx,
                            prev_p2, deltas_f, marg, deltas_out, stream);
    } else {
        // Tier B: fp16 message + fp16 m_buf
        unsigned short* message = (unsigned short*)p;
        unsigned short* m_buf = (unsigned short*)(p + msg_f16);
        run_pipeline<unsigned short>(d_in, E, N, message, m_buf, node_agg, wp,
                                     deg, row_ptr, cursor, col_idx,
                                     prev_p2, deltas_f, marg, deltas_out, stream);
    }
}